// Round 5
// baseline (2177.657 us; speedup 1.0000x reference)
//
#include <hip/hip_runtime.h>

// Problem constants (fixed by reference)
#define N_TOKENS  65536
#define CODE_DIM  768
#define NUM_CODES 4096

#define MARGIN 0.006f
#define FLTMAX 3.4028235e38f

typedef __attribute__((ext_vector_type(8))) short bf16x8;
typedef __attribute__((ext_vector_type(4))) float f32x4;

// ---------------------------------------------------------------- helpers
__device__ __forceinline__ unsigned short f2bf(float f) {
  unsigned int u = __float_as_uint(f);
  unsigned int r = (u + 0x7fffu + ((u >> 16) & 1u)) >> 16;  // RN-even
  return (unsigned short)r;
}
__device__ __forceinline__ float bf2f(unsigned short h) {
  return __uint_as_float(((unsigned int)h) << 16);
}
__device__ __forceinline__ void gl2lds16(const void* g, void* l) {
  __builtin_amdgcn_global_load_lds(
      (const __attribute__((address_space(1))) unsigned int*)g,
      (__attribute__((address_space(3))) unsigned int*)l, 16, 0, 0);
}

// ---------------------------------------------------------------- convert
// One wave per row: split fp32 -> (hi, lo) bf16 and compute squared norm.
__global__ __launch_bounds__(256) void vq_convert_kernel(
    const float* __restrict__ x, const float* __restrict__ cb,
    unsigned short* __restrict__ xh, unsigned short* __restrict__ xl,
    unsigned short* __restrict__ cbh, unsigned short* __restrict__ cbl,
    float* __restrict__ x2, float* __restrict__ c2, int* __restrict__ fcnt) {
  if (blockIdx.x == 0 && threadIdx.x == 0) *fcnt = 0;
  const int wave = threadIdx.x >> 6;
  const int lane = threadIdx.x & 63;
  const int row  = blockIdx.x * 4 + wave;
  const float* src;
  unsigned short *hdst, *ldst;
  float* ndst;
  if (row < N_TOKENS) {
    src = x + (size_t)row * CODE_DIM;
    hdst = xh + (size_t)row * CODE_DIM;
    ldst = xl + (size_t)row * CODE_DIM;
    ndst = x2 + row;
  } else {
    const int r = row - N_TOKENS;
    if (r >= NUM_CODES) return;
    src = cb + (size_t)r * CODE_DIM;
    hdst = cbh + (size_t)r * CODE_DIM;
    ldst = cbl + (size_t)r * CODE_DIM;
    ndst = c2 + r;
  }
  const float4* s4 = (const float4*)src;
  ushort4* h4 = (ushort4*)hdst;
  ushort4* l4 = (ushort4*)ldst;
  float acc = 0.f;
#pragma unroll
  for (int i = 0; i < 3; ++i) {
    float4 f = s4[lane + 64 * i];
    ushort4 h, l;
    h.x = f2bf(f.x); l.x = f2bf(f.x - bf2f(h.x));
    h.y = f2bf(f.y); l.y = f2bf(f.y - bf2f(h.y));
    h.z = f2bf(f.z); l.z = f2bf(f.z - bf2f(h.z));
    h.w = f2bf(f.w); l.w = f2bf(f.w - bf2f(h.w));
    h4[lane + 64 * i] = h;
    l4[lane + 64 * i] = l;
    acc += (f.x * f.x + f.y * f.y) + (f.z * f.z + f.w * f.w);
  }
#pragma unroll
  for (int off = 32; off > 0; off >>= 1) acc += __shfl_down(acc, off, 64);
  if (lane == 0) *ndst = acc;
}

// ---------------------------------------------------------------- phase 1
// Split-bf16 MFMA argmin. Block = 128 tokens x 128-code tiles (32 kt iters),
// 256 threads / 4 waves as 2x2; wave tile 64x64 = acc[4][4], 48 MFMA of
// 16x16x32 per K=32 step (pass-outer hh,hl,lh -- per-acc order unchanged).
// LDS = 2x16KB (A) + 2x16KB (B) + 3KB red ~= 67 KB  ->  TWO blocks per CU
// (grid 512 = 2/CU exact). The two co-resident blocks have independent
// barriers: while one block's waves are in the read/barrier convoy, the
// other block's wave on the same SIMD issues MFMA (m114 overlap). This is
// the lever: the single-block lockstep had ~zero LDS/MFMA overlap.
// 2 LDS slots, depth-1 prefetch (A-stage after first read cluster, B-stage
// after the hh pass), ONE barrier per step, vmcnt(0) drains loads issued
// ~1200+ cyc earlier.
// LDS row layout: 64 shorts/row = 8 chunks of 8 bf16; stored chunk position
// p holds logical chunk c = p ^ (row&7); c<4 -> hi k-quads, c>=4 -> lo.
// XOR applied to the *global* source so LDS dests stay lane-linear.
#define BT 128
#define KTILE 128
#define NKT (NUM_CODES / KTILE)          // 32
#define NSTEP (CODE_DIM / 32)            // 24 per kt
#define TOTSTEP (NKT * NSTEP)            // 768

__global__ __launch_bounds__(256, 2) void vq_mfma_kernel(
    const unsigned short* __restrict__ xh, const unsigned short* __restrict__ xl,
    const unsigned short* __restrict__ cbh, const unsigned short* __restrict__ cbl,
    const float* __restrict__ c2, int* __restrict__ out_idx,
    int* __restrict__ fcnt, int* __restrict__ flist) {
  __shared__ __align__(16) unsigned short sA[2][BT * 64];     // 2 x 16 KiB
  __shared__ __align__(16) unsigned short sB[2][KTILE * 64];  // 2 x 16 KiB
  __shared__ float redv[256], redsv[256];
  __shared__ int   redi[256];

  const int tid = threadIdx.x;
  const int wave = tid >> 6, lane = tid & 63;
  const int l15 = lane & 15, quad = lane >> 4;
  const int wr = wave >> 1, wc = wave & 1;  // 2x2 wave grid
  const int tokBase = blockIdx.x * BT;

  // ---- staging per-lane constants
  // each inst covers 8 rows x 8 chunk-positions; lane l -> row +(l>>3), pos l&7.
  // logical chunk c = pos ^ (row&7) = (l&7) ^ (l>>3)
  const int lr = lane >> 3;
  const int cc = (lane & 7) ^ lr;
  const int hsel = cc >> 2;            // 0 = hi source, 1 = lo source
  const int coff = (cc & 3) * 8;       // k sub-offset in shorts
  const unsigned short* pAsrc = hsel ? xl : xh;
  const unsigned short* pBsrc = hsel ? cbl : cbh;
  const size_t aOff = (size_t)(tokBase + wave * 32 + lr) * CODE_DIM + coff;
  const size_t bOff = (size_t)(wave * 32 + lr) * CODE_DIM + coff;

  // ---- fragment read bases (shorts). hi chunk quad at pos quad^(l15&7);
  // lo chunk at pos ^4 (= shorts offset ^32).
  const int aposh = (quad ^ (l15 & 7)) * 8;
  const int aBaseH = (wr * 64 + l15) * 64 + aposh;
  const int aBaseL = (wr * 64 + l15) * 64 + (aposh ^ 32);
  const int bBaseH = (wc * 64 + l15) * 64 + aposh;
  const int bBaseL = (wc * 64 + l15) * 64 + (aposh ^ 32);

  float v[4][4], sv[4][4];
  int bi[4][4];
#pragma unroll
  for (int i = 0; i < 4; ++i)
#pragma unroll
    for (int r = 0; r < 4; ++r) { v[i][r] = FLTMAX; sv[i][r] = FLTMAX; bi[i][r] = 0; }

  // ---- prologue: stage step 0 into slot 0 (8 insts/wave, 32 rows each of A,B)
  {
#pragma unroll
    for (int t = 0; t < 4; ++t)
      gl2lds16(pAsrc + aOff + (size_t)t * (8 * CODE_DIM),
               &sA[0][(wave * 32 + t * 8) * 64]);
#pragma unroll
    for (int t = 0; t < 4; ++t)
      gl2lds16(pBsrc + bOff + (size_t)t * (8 * CODE_DIM),
               &sB[0][(wave * 32 + t * 8) * 64]);
  }
  asm volatile("s_waitcnt vmcnt(0)" ::: "memory");
  __builtin_amdgcn_s_barrier();
  __builtin_amdgcn_sched_barrier(0);

  for (int kt = 0; kt < NKT; ++kt) {
    f32x4 acc[4][4];
#pragma unroll
    for (int i = 0; i < 4; ++i)
#pragma unroll
      for (int j = 0; j < 4; ++j) acc[i][j] = (f32x4){0.f, 0.f, 0.f, 0.f};

    for (int ksq = 0; ksq < NSTEP; ++ksq) {
      const int gstep = kt * NSTEP + ksq;
      const int cur = gstep & 1;
      const bool more = (gstep < TOTSTEP - 1);
      const int ns = gstep + 1;
      const int nk0 = (ns % NSTEP) * 32;
      const size_t nbb = (size_t)(ns / NSTEP) * (KTILE * (size_t)CODE_DIM);
      const unsigned short* As = sA[cur];
      const unsigned short* Bs = sB[cur];

      bf16x8 fah[4], fal[4], fbh[4], fbl[4];
#pragma unroll
      for (int i = 0; i < 4; ++i) fah[i] = *(const bf16x8*)(As + aBaseH + i * 1024);
#pragma unroll
      for (int j = 0; j < 4; ++j) fbh[j] = *(const bf16x8*)(Bs + bBaseH + j * 1024);

      // stage A for step p+1 (drained at end of this step)
      if (more) {
#pragma unroll
        for (int t = 0; t < 4; ++t)
          gl2lds16(pAsrc + aOff + (size_t)t * (8 * CODE_DIM) + nk0,
                   &sA[cur ^ 1][(wave * 32 + t * 8) * 64]);
      }

      __builtin_amdgcn_s_setprio(1);
#pragma unroll
      for (int i = 0; i < 4; ++i)
#pragma unroll
        for (int j = 0; j < 4; ++j)
          acc[i][j] = __builtin_amdgcn_mfma_f32_16x16x32_bf16(fah[i], fbh[j], acc[i][j], 0, 0, 0);
      __builtin_amdgcn_s_setprio(0);

      // stage B for step p+1
      if (more) {
#pragma unroll
        for (int t = 0; t < 4; ++t)
          gl2lds16(pBsrc + nbb + bOff + (size_t)t * (8 * CODE_DIM) + nk0,
                   &sB[cur ^ 1][(wave * 32 + t * 8) * 64]);
      }

#pragma unroll
      for (int j = 0; j < 4; ++j) fbl[j] = *(const bf16x8*)(Bs + bBaseL + j * 1024);
      __builtin_amdgcn_s_setprio(1);
#pragma unroll
      for (int i = 0; i < 4; ++i)
#pragma unroll
        for (int j = 0; j < 4; ++j)
          acc[i][j] = __builtin_amdgcn_mfma_f32_16x16x32_bf16(fah[i], fbl[j], acc[i][j], 0, 0, 0);
      __builtin_amdgcn_s_setprio(0);

#pragma unroll
      for (int i = 0; i < 4; ++i) fal[i] = *(const bf16x8*)(As + aBaseL + i * 1024);
      __builtin_amdgcn_s_setprio(1);
#pragma unroll
      for (int i = 0; i < 4; ++i)
#pragma unroll
        for (int j = 0; j < 4; ++j)
          acc[i][j] = __builtin_amdgcn_mfma_f32_16x16x32_bf16(fal[i], fbh[j], acc[i][j], 0, 0, 0);
      __builtin_amdgcn_s_setprio(0);

      // drain own stage (issued ~1200+ cyc earlier), slot swap
      asm volatile("s_waitcnt vmcnt(0)" ::: "memory");
      __builtin_amdgcn_s_barrier();
      __builtin_amdgcn_sched_barrier(0);
    }

    // epilogue: s = c2 - 2*dot; maintain (best, second, idx) per token slot
    const int kbase = kt * KTILE;
#pragma unroll
    for (int j = 0; j < 4; ++j) {
      const int kcol = kbase + wc * 64 + j * 16 + l15;
      const float c2j = c2[kcol];
#pragma unroll
      for (int i = 0; i < 4; ++i)
#pragma unroll
        for (int r = 0; r < 4; ++r) {
          float s = fmaf(-2.0f, acc[i][j][r], c2j);
          float vo = v[i][r];
          sv[i][r] = fminf(sv[i][r], fmaxf(s, vo));  // med3(s, v, sv)
          bool lt = s < vo;
          v[i][r]  = lt ? s : vo;
          bi[i][r] = lt ? kcol : bi[i][r];
        }
    }
  }

  // butterfly reduce across the 16 lanes sharing a token row
#pragma unroll
  for (int i = 0; i < 4; ++i)
#pragma unroll
    for (int r = 0; r < 4; ++r) {
      float vv = v[i][r], svv = sv[i][r];
      int ii = bi[i][r];
#pragma unroll
      for (int m = 1; m < 16; m <<= 1) {
        float ov = __shfl_xor(vv, m, 64);
        float osv = __shfl_xor(svv, m, 64);
        int oi = __shfl_xor(ii, m, 64);
        float nsv = fminf(fminf(svv, osv), fmaxf(vv, ov));
        bool take = (ov < vv) || (ov == vv && oi < ii);
        vv = take ? ov : vv;
        ii = take ? oi : ii;
        svv = nsv;
      }
      if (l15 == 0) {
        int row = wr * 64 + i * 16 + quad * 4 + r;
        redv[row * 2 + wc] = vv;
        redsv[row * 2 + wc] = svv;
        redi[row * 2 + wc] = ii;
      }
    }
  __syncthreads();
  if (tid < 128) {
    float v0 = redv[tid * 2], v1 = redv[tid * 2 + 1];
    float s0 = redsv[tid * 2], s1 = redsv[tid * 2 + 1];
    int i0 = redi[tid * 2], i1 = redi[tid * 2 + 1];
    bool take = (v1 < v0) || (v1 == v0 && i1 < i0);
    float bv = take ? v1 : v0;
    int bidx = take ? i1 : i0;
    float bsv = fminf(fminf(s0, s1), fmaxf(v0, v1));
    out_idx[tokBase + tid] = bidx;
    if (bsv - bv < MARGIN) {
      int p = atomicAdd(fcnt, 1);
      flist[p] = tokBase + tid;
    }
  }
}

// ---------------------------------------------------------------- rescan
// Exact fp32 full scan for flagged tokens, 4 tokens per block-group so the
// 12.6 MB codebook read is shared 4-way. Math & scan order per token are
// identical to the single-token version.
__global__ __launch_bounds__(256) void vq_rescan_kernel(
    const float* __restrict__ x, const float* __restrict__ cb,
    const float* __restrict__ x2, const float* __restrict__ c2,
    const int* __restrict__ fcnt, const int* __restrict__ flist,
    int* __restrict__ out_idx) {
  __shared__ float xs[4][CODE_DIM];
  __shared__ float rv[256];
  __shared__ int ri[256];
  const int nf = *fcnt;
  const int ngr = (nf + 3) >> 2;
  for (int g = blockIdx.x; g < ngr; g += gridDim.x) {
    const int base = g * 4;
    int tok[4];
#pragma unroll
    for (int t = 0; t < 4; ++t) tok[t] = flist[min(base + t, nf - 1)];
    __syncthreads();  // previous group's xs/rv readers done
    if (threadIdx.x < 192) {
#pragma unroll
      for (int t = 0; t < 4; ++t)
        ((float4*)xs[t])[threadIdx.x] =
            ((const float4*)(x + (size_t)tok[t] * CODE_DIM))[threadIdx.x];
    }
    __syncthreads();
    float bv[4]; int bidx[4];
#pragma unroll
    for (int t = 0; t < 4; ++t) { bv[t] = FLTMAX; bidx[t] = 0; }
    for (int kk = 0; kk < NUM_CODES / 256; ++kk) {
      const int k = kk * 256 + threadIdx.x;
      const float4* crow = (const float4*)(cb + (size_t)k * CODE_DIM);
      float a0 = 0.f, a1 = 0.f, a2 = 0.f, a3 = 0.f;
      for (int c = 0; c < CODE_DIM / 4; ++c) {
        float4 cv = crow[c];
        float4 x0 = ((float4*)xs[0])[c];
        float4 x1 = ((float4*)xs[1])[c];
        float4 x2v = ((float4*)xs[2])[c];
        float4 x3 = ((float4*)xs[3])[c];
        a0 += (x0.x * cv.x + x0.y * cv.y) + (x0.z * cv.z + x0.w * cv.w);
        a1 += (x1.x * cv.x + x1.y * cv.y) + (x1.z * cv.z + x1.w * cv.w);
        a2 += (x2v.x * cv.x + x2v.y * cv.y) + (x2v.z * cv.z + x2v.w * cv.w);
        a3 += (x3.x * cv.x + x3.y * cv.y) + (x3.z * cv.z + x3.w * cv.w);
      }
      const float c2k = c2[k];
      float d0 = (x2[tok[0]] + c2k) - 2.0f * a0;
      float d1 = (x2[tok[1]] + c2k) - 2.0f * a1;
      float d2 = (x2[tok[2]] + c2k) - 2.0f * a2;
      float d3 = (x2[tok[3]] + c2k) - 2.0f * a3;
      if (d0 < bv[0]) { bv[0] = d0; bidx[0] = k; }
      if (d1 < bv[1]) { bv[1] = d1; bidx[1] = k; }
      if (d2 < bv[2]) { bv[2] = d2; bidx[2] = k; }
      if (d3 < bv[3]) { bv[3] = d3; bidx[3] = k; }
    }
#pragma unroll
    for (int t = 0; t < 4; ++t) {
      __syncthreads();
      rv[threadIdx.x] = bv[t];
      ri[threadIdx.x] = bidx[t];
      __syncthreads();
      for (int s = 128; s > 0; s >>= 1) {
        if (threadIdx.x < s) {
          float ov = rv[threadIdx.x + s];
          int oi = ri[threadIdx.x + s];
          if (ov < rv[threadIdx.x] ||
              (ov == rv[threadIdx.x] && oi < ri[threadIdx.x])) {
            rv[threadIdx.x] = ov;
            ri[threadIdx.x] = oi;
          }
        }
        __syncthreads();
      }
      if (threadIdx.x == 0 && base + t < nf) out_idx[tok[t]] = ri[0];
    }
  }
}

// ---------------------------------------------------------------- gather
__global__ __launch_bounds__(256) void vq_gather_kernel(
    const float* __restrict__ cb, const int* __restrict__ idx,
    float* __restrict__ out) {
  const int wave = threadIdx.x >> 6;
  const int lane = threadIdx.x & 63;
  const int token = blockIdx.x * 4 + wave;
  const int k = idx[token];
  const float4* src = (const float4*)(cb + (size_t)k * CODE_DIM);
  float4* dst = (float4*)(out + (size_t)token * CODE_DIM);
#pragma unroll
  for (int i = 0; i < 3; ++i) dst[lane + 64 * i] = src[lane + 64 * i];
  if (lane == 0) out[(size_t)N_TOKENS * CODE_DIM + token] = (float)k;
}

// ================================================================ fallback
// Round-1 fp32 path (used only if ws_size is too small for the split buffers)
#define MT 64
#define KT 128
#define DT 32
#define LDSTRIDE 36

__global__ __launch_bounds__(256) void vq_norms_kernel(
    const float* __restrict__ x, const float* __restrict__ cb,
    float* __restrict__ x2, float* __restrict__ c2) {
  const int wave = threadIdx.x >> 6;
  const int lane = threadIdx.x & 63;
  const int row = blockIdx.x * 4 + wave;
  const float* src;
  float* dst;
  if (row < N_TOKENS) {
    src = x + (size_t)row * CODE_DIM;
    dst = x2 + row;
  } else {
    const int r = row - N_TOKENS;
    if (r >= NUM_CODES) return;
    src = cb + (size_t)r * CODE_DIM;
    dst = c2 + r;
  }
  const float4* s4 = (const float4*)src;
  float acc = 0.f;
#pragma unroll
  for (int i = 0; i < 3; ++i) {
    float4 vv = s4[lane + 64 * i];
    acc += (vv.x * vv.x + vv.y * vv.y) + (vv.z * vv.z + vv.w * vv.w);
  }
#pragma unroll
  for (int off = 32; off > 0; off >>= 1) acc += __shfl_down(acc, off, 64);
  if (lane == 0) *dst = acc;
}

__global__ __launch_bounds__(256) void vq_argmin_kernel(
    const float* __restrict__ x, const float* __restrict__ cb,
    const float* __restrict__ x2, const float* __restrict__ c2,
    int* __restrict__ out_idx) {
  __shared__ float xs[MT * LDSTRIDE];
  __shared__ float cs[KT * LDSTRIDE];
  __shared__ float x2s[MT];
  __shared__ float c2s[KT];
  const int tid = threadIdx.x;
  const int tx = tid & 15;
  const int ty = tid >> 4;
  const int tokBase = blockIdx.x * MT;
  if (tid < MT) x2s[tid] = x2[tokBase + tid];
  float bestv[4];
  int besti[4];
#pragma unroll
  for (int i = 0; i < 4; ++i) { bestv[i] = FLTMAX; besti[i] = 0; }
  const float4* xg = (const float4*)x;
  const float4* cg = (const float4*)cb;
  for (int kt = 0; kt < NUM_CODES / KT; ++kt) {
    const int kBase = kt * KT;
    __syncthreads();
    if (tid < KT) c2s[tid] = c2[kBase + tid];
    float acc[4][8];
#pragma unroll
    for (int i = 0; i < 4; ++i)
#pragma unroll
      for (int j = 0; j < 8; ++j) acc[i][j] = 0.f;
    for (int dc = 0; dc < CODE_DIM / DT; ++dc) {
      __syncthreads();
#pragma unroll
      for (int r = 0; r < 2; ++r) {
        int fidx = tid + 256 * r;
        int row = fidx >> 3, c4 = fidx & 7;
        float4 vv = xg[(size_t)(tokBase + row) * (CODE_DIM / 4) + dc * 8 + c4];
        *(float4*)&xs[row * LDSTRIDE + c4 * 4] = vv;
      }
#pragma unroll
      for (int r = 0; r < 4; ++r) {
        int fidx = tid + 256 * r;
        int row = fidx >> 3, c4 = fidx & 7;
        float4 vv = cg[(size_t)(kBase + row) * (CODE_DIM / 4) + dc * 8 + c4];
        *(float4*)&cs[row * LDSTRIDE + c4 * 4] = vv;
      }
      __syncthreads();
#pragma unroll
      for (int dd = 0; dd < DT / 4; ++dd) {
        float4 xv[4], cv[8];
#pragma unroll
        for (int i = 0; i < 4; ++i)
          xv[i] = *(const float4*)&xs[(ty + 16 * i) * LDSTRIDE + dd * 4];
#pragma unroll
        for (int j = 0; j < 8; ++j)
          cv[j] = *(const float4*)&cs[(tx + 16 * j) * LDSTRIDE + dd * 4];
#pragma unroll
        for (int i = 0; i < 4; ++i)
#pragma unroll
          for (int j = 0; j < 8; ++j)
            acc[i][j] += (xv[i].x * cv[j].x + xv[i].y * cv[j].y) +
                         (xv[i].z * cv[j].z + xv[i].w * cv[j].w);
      }
    }
#pragma unroll
    for (int i = 0; i < 4; ++i) {
      const float xx = x2s[ty + 16 * i];
#pragma unroll
      for (int j = 0; j < 8; ++j) {
        float dist = (xx + c2s[tx + 16 * j]) - 2.0f * acc[i][j];
        int k = kBase + tx + 16 * j;
        if (dist < bestv[i]) { bestv[i] = dist; besti[i] = k; }
      }
    }
  }
  __syncthreads();
  float* rdv = xs;
  int* rdi = (int*)cs;
#pragma unroll
  for (int i = 0; i < 4; ++i) {
    const int m = ty + 16 * i;
    rdv[m * 16 + tx] = bestv[i];
    rdi[m * 16 + tx] = besti[i];
  }
  __syncthreads();
  if (tid < MT) {
    float bv = rdv[tid * 16];
    int bidx = rdi[tid * 16];
#pragma unroll
    for (int t = 1; t < 16; ++t) {
      float vv = rdv[tid * 16 + t];
      int kk = rdi[tid * 16 + t];
      if (vv < bv || (vv == bv && kk < bidx)) { bv = vv; bidx = kk; }
    }
    out_idx[tokBase + tid] = bidx;
  }
}

// ---------------------------------------------------------------- launch
extern "C" void kernel_launch(void* const* d_in, const int* in_sizes, int n_in,
                              void* d_out, int out_size, void* d_ws, size_t ws_size,
                              hipStream_t stream) {
  (void)in_sizes; (void)n_in; (void)out_size;
  const float* x = (const float*)d_in[0];
  const float* cb = (const float*)d_in[1];
  float* out = (float*)d_out;

  // ws carve (MFMA path)
  char* w = (char*)d_ws;
  unsigned short* xh = (unsigned short*)w;  w += (size_t)N_TOKENS * CODE_DIM * 2;
  unsigned short* xl = (unsigned short*)w;  w += (size_t)N_TOKENS * CODE_DIM * 2;
  unsigned short* cbh = (unsigned short*)w; w += (size_t)NUM_CODES * CODE_DIM * 2;
  unsigned short* cbl = (unsigned short*)w; w += (size_t)NUM_CODES * CODE_DIM * 2;
  float* x2 = (float*)w;  w += (size_t)N_TOKENS * 4;
  float* c2 = (float*)w;  w += (size_t)NUM_CODES * 4;
  int* idx = (int*)w;     w += (size_t)N_TOKENS * 4;
  int* flist = (int*)w;   w += (size_t)N_TOKENS * 4;
  int* fcnt = (int*)w;    w += 256;
  const size_t need = (size_t)(w - (char*)d_ws);

  if (ws_size >= need) {
    vq_convert_kernel<<<(N_TOKENS + NUM_CODES) / 4, 256, 0, stream>>>(
        x, cb, xh, xl, cbh, cbl, x2, c2, fcnt);
    vq_mfma_kernel<<<N_TOKENS / BT, 256, 0, stream>>>(
        xh, xl, cbh, cbl, c2, idx, fcnt, flist);
    vq_rescan_kernel<<<512, 256, 0, stream>>>(x, cb, x2, c2, fcnt, flist, idx);
    vq_gather_kernel<<<N_TOKENS / 4, 256, 0, stream>>>(cb, idx, out);
  } else {
    // fallback: round-1 fp32 path
    float* fx2 = (float*)d_ws;
    float* fc2 = fx2 + N_TOKENS;
    int* fidx = (int*)(fc2 + NUM_CODES);
    vq_norms_kernel<<<(N_TOKENS + NUM_CODES + 3) / 4, 256, 0, stream>>>(x, cb, fx2, fc2);
    vq_argmin_kernel<<<N_TOKENS / MT, 256, 0, stream>>>(x, cb, fx2, fc2, fidx);
    vq_gather_kernel<<<N_TOKENS / 4, 256, 0, stream>>>(cb, fidx, out);
  }
}

// Round 6
// 1727.617 us; speedup vs baseline: 1.2605x; 1.2605x over previous
//
#include <hip/hip_runtime.h>

// Problem constants (fixed by reference)
#define N_TOKENS  65536
#define CODE_DIM  768
#define NUM_CODES 4096

#define MARGIN 0.12f
#define FLTMAX 3.4028235e38f

typedef __attribute__((ext_vector_type(8))) _Float16 f16x8;
typedef __attribute__((ext_vector_type(4))) float f32x4;

// ---------------------------------------------------------------- helpers
__device__ __forceinline__ unsigned short f2h(float f) {
  _Float16 h = (_Float16)f;  // RN
  return *(unsigned short*)&h;
}
__device__ __forceinline__ void gl2lds16(const void* g, void* l) {
  __builtin_amdgcn_global_load_lds(
      (const __attribute__((address_space(1))) unsigned int*)g,
      (__attribute__((address_space(3))) unsigned int*)l, 16, 0, 0);
}

// ---------------------------------------------------------------- convert
// One wave per row: fp32 -> fp16 (single) and squared norm (fp32 exact).
__global__ __launch_bounds__(256) void vq_convert_kernel(
    const float* __restrict__ x, const float* __restrict__ cb,
    unsigned short* __restrict__ xh, unsigned short* __restrict__ ch,
    float* __restrict__ x2, float* __restrict__ c2, int* __restrict__ fcnt) {
  if (blockIdx.x == 0 && threadIdx.x == 0) *fcnt = 0;
  const int wave = threadIdx.x >> 6;
  const int lane = threadIdx.x & 63;
  const int row  = blockIdx.x * 4 + wave;
  const float* src;
  unsigned short* hdst;
  float* ndst;
  if (row < N_TOKENS) {
    src = x + (size_t)row * CODE_DIM;
    hdst = xh + (size_t)row * CODE_DIM;
    ndst = x2 + row;
  } else {
    const int r = row - N_TOKENS;
    if (r >= NUM_CODES) return;
    src = cb + (size_t)r * CODE_DIM;
    hdst = ch + (size_t)r * CODE_DIM;
    ndst = c2 + r;
  }
  const float4* s4 = (const float4*)src;
  ushort4* h4 = (ushort4*)hdst;
  float acc = 0.f;
#pragma unroll
  for (int i = 0; i < 3; ++i) {
    float4 f = s4[lane + 64 * i];
    ushort4 h;
    h.x = f2h(f.x); h.y = f2h(f.y); h.z = f2h(f.z); h.w = f2h(f.w);
    h4[lane + 64 * i] = h;
    acc += (f.x * f.x + f.y * f.y) + (f.z * f.z + f.w * f.w);
  }
#pragma unroll
  for (int off = 32; off > 0; off >>= 1) acc += __shfl_down(acc, off, 64);
  if (lane == 0) *ndst = acc;
}

// ---------------------------------------------------------------- phase 1
// SINGLE-PASS fp16 MFMA argmin. Block = 256 tokens x 256-code tiles (16 kt).
// 8 waves as 4x2; wave tile 64x128 = acc[4][8]. K-step = 64 (two K=32
// sub-slots e=0/e=1), 64 MFMA of 16x16x32_f16 per wave per step. 2 LDS
// slots each for A and B (32 KB each, rows of 64 shorts = 8 chunks of 8 f16
// covering the K=64 window, chunk at stored pos p holds logical chunk
// p ^ (row&7)). Depth-1 prefetch issued at step top, ONE barrier per step,
// vmcnt(0) drains loads issued a full step earlier. XOR applied to the
// *global* source so LDS dests stay lane-linear (global_load_lds).
// fp16 error handled by margin+exact-rescan: sigma_diff(dist, 2 candidates)
// ~ 0.016; MARGIN = 0.12 ~ 7.7 sigma.
#define BT 256
#define KTILE 256
#define NKT (NUM_CODES / KTILE)          // 16
#define NST (CODE_DIM / 64)              // 12 K=64 steps per kt
#define TOT (NKT * NST)                  // 192

__global__ __launch_bounds__(512, 2) void vq_mfma_kernel(
    const unsigned short* __restrict__ xh, const unsigned short* __restrict__ ch,
    const float* __restrict__ c2, int* __restrict__ out_idx,
    int* __restrict__ fcnt, int* __restrict__ flist) {
  __shared__ __align__(16) unsigned short sA[2][BT * 64];     // 2 x 32 KiB
  __shared__ __align__(16) unsigned short sB[2][KTILE * 64];  // 2 x 32 KiB
  __shared__ float redv[512], redsv[512];
  __shared__ int   redi[512];

  const int tid = threadIdx.x;
  const int wave = tid >> 6, lane = tid & 63;
  const int l15 = lane & 15, quad = lane >> 4;
  const int wr = wave >> 1, wc = wave & 1;  // 4x2 wave grid
  const int tokBase = blockIdx.x * BT;

  // ---- staging per-lane constants (each inst: 8 rows x 8 chunk-positions)
  const int lr = lane >> 3;
  const int cSrc = (lane & 7) ^ lr;    // logical chunk staged by this lane
  const size_t aOff = (size_t)(tokBase + wave * 32 + lr) * CODE_DIM + cSrc * 8;
  const size_t bOff = (size_t)(wave * 32 + lr) * CODE_DIM + cSrc * 8;

  // ---- fragment read bases (shorts). e=0 sub-slot: chunk quad at pos
  // quad^(l15&7); e=1: chunk 4+quad at pos ^4 (= shorts offset ^32).
  const int apos = (quad ^ (l15 & 7)) * 8;
  const int aB0 = (wr * 64 + l15) * 64 + apos;
  const int aB1 = (wr * 64 + l15) * 64 + (apos ^ 32);
  const int bB0 = (wc * 128 + l15) * 64 + apos;
  const int bB1 = (wc * 128 + l15) * 64 + (apos ^ 32);

  float v[4][4], sv[4][4];
  int bi[4][4];
#pragma unroll
  for (int i = 0; i < 4; ++i)
#pragma unroll
    for (int r = 0; r < 4; ++r) { v[i][r] = FLTMAX; sv[i][r] = FLTMAX; bi[i][r] = 0; }

  // stage one K=64 step (8 insts/wave: 32 rows of A, 32 rows of B)
  auto STAGE = [&](int slot, int s) {
    const int kw = (s % NST) * 64;
    const size_t rb = (size_t)(s / NST) * (KTILE * (size_t)CODE_DIM);
#pragma unroll
    for (int t = 0; t < 4; ++t)
      gl2lds16(xh + aOff + (size_t)t * (8 * CODE_DIM) + kw,
               &sA[slot][(wave * 32 + t * 8) * 64]);
#pragma unroll
    for (int t = 0; t < 4; ++t)
      gl2lds16(ch + rb + bOff + (size_t)t * (8 * CODE_DIM) + kw,
               &sB[slot][(wave * 32 + t * 8) * 64]);
  };

  // ---- prologue: stage step 0 into slot 0
  STAGE(0, 0);
  asm volatile("s_waitcnt vmcnt(0)" ::: "memory");
  __builtin_amdgcn_s_barrier();
  __builtin_amdgcn_sched_barrier(0);

  for (int kt = 0; kt < NKT; ++kt) {
    f32x4 acc[4][8];
#pragma unroll
    for (int i = 0; i < 4; ++i)
#pragma unroll
      for (int j = 0; j < 8; ++j) acc[i][j] = (f32x4){0.f, 0.f, 0.f, 0.f};

    for (int ks = 0; ks < NST; ++ks) {
      const int gstep = kt * NST + ks;
      const int cur = gstep & 1;
      const unsigned short* As = sA[cur];
      const unsigned short* Bs = sB[cur];
      if (gstep < TOT - 1) STAGE(cur ^ 1, gstep + 1);  // drained at step end

      f16x8 fa[4], fb[8];
      // ---- sub-slot e = 0 (K dims 0..31 of window)
#pragma unroll
      for (int i = 0; i < 4; ++i) fa[i] = *(const f16x8*)(As + aB0 + i * 1024);
#pragma unroll
      for (int j = 0; j < 8; ++j) fb[j] = *(const f16x8*)(Bs + bB0 + j * 1024);
      __builtin_amdgcn_s_setprio(1);
#pragma unroll
      for (int i = 0; i < 4; ++i)
#pragma unroll
        for (int j = 0; j < 8; ++j)
          acc[i][j] = __builtin_amdgcn_mfma_f32_16x16x32_f16(fa[i], fb[j], acc[i][j], 0, 0, 0);
      __builtin_amdgcn_s_setprio(0);
      // ---- sub-slot e = 1 (K dims 32..63)
#pragma unroll
      for (int i = 0; i < 4; ++i) fa[i] = *(const f16x8*)(As + aB1 + i * 1024);
#pragma unroll
      for (int j = 0; j < 8; ++j) fb[j] = *(const f16x8*)(Bs + bB1 + j * 1024);
      __builtin_amdgcn_s_setprio(1);
#pragma unroll
      for (int i = 0; i < 4; ++i)
#pragma unroll
        for (int j = 0; j < 8; ++j)
          acc[i][j] = __builtin_amdgcn_mfma_f32_16x16x32_f16(fa[i], fb[j], acc[i][j], 0, 0, 0);
      __builtin_amdgcn_s_setprio(0);

      // drain own stage (issued a full step ago), slot swap
      asm volatile("s_waitcnt vmcnt(0)" ::: "memory");
      __builtin_amdgcn_s_barrier();
      __builtin_amdgcn_sched_barrier(0);
    }

    // epilogue: s = c2 - 2*dot; maintain (best, second, idx) per token slot
    const int kbase = kt * KTILE;
#pragma unroll
    for (int j = 0; j < 8; ++j) {
      const int kcol = kbase + wc * 128 + j * 16 + l15;
      const float c2j = c2[kcol];
#pragma unroll
      for (int i = 0; i < 4; ++i)
#pragma unroll
        for (int r = 0; r < 4; ++r) {
          float s = fmaf(-2.0f, acc[i][j][r], c2j);
          float vo = v[i][r];
          sv[i][r] = fminf(sv[i][r], fmaxf(s, vo));  // med3(s, v, sv)
          bool lt = s < vo;
          v[i][r]  = lt ? s : vo;
          bi[i][r] = lt ? kcol : bi[i][r];
        }
    }
  }

  // butterfly reduce across the 16 lanes sharing a token row
#pragma unroll
  for (int i = 0; i < 4; ++i)
#pragma unroll
    for (int r = 0; r < 4; ++r) {
      float vv = v[i][r], svv = sv[i][r];
      int ii = bi[i][r];
#pragma unroll
      for (int m = 1; m < 16; m <<= 1) {
        float ov = __shfl_xor(vv, m, 64);
        float osv = __shfl_xor(svv, m, 64);
        int oi = __shfl_xor(ii, m, 64);
        float nsv = fminf(fminf(svv, osv), fmaxf(vv, ov));
        bool take = (ov < vv) || (ov == vv && oi < ii);
        vv = take ? ov : vv;
        ii = take ? oi : ii;
        svv = nsv;
      }
      if (l15 == 0) {
        int row = wr * 64 + i * 16 + quad * 4 + r;
        redv[row * 2 + wc] = vv;
        redsv[row * 2 + wc] = svv;
        redi[row * 2 + wc] = ii;
      }
    }
  __syncthreads();
  if (tid < 256) {
    float v0 = redv[tid * 2], v1 = redv[tid * 2 + 1];
    float s0 = redsv[tid * 2], s1 = redsv[tid * 2 + 1];
    int i0 = redi[tid * 2], i1 = redi[tid * 2 + 1];
    bool take = (v1 < v0) || (v1 == v0 && i1 < i0);
    float bv = take ? v1 : v0;
    int bidx = take ? i1 : i0;
    float bsv = fminf(fminf(s0, s1), fmaxf(v0, v1));
    out_idx[tokBase + tid] = bidx;
    if (bsv - bv < MARGIN) {
      int p = atomicAdd(fcnt, 1);
      flist[p] = tokBase + tid;
    }
  }
}

// ---------------------------------------------------------------- rescan
// Exact fp32 full scan for flagged tokens, 8 tokens per block-group so the
// 12.6 MB codebook read is shared 8-way. Per-token math & order identical.
__global__ __launch_bounds__(256) void vq_rescan_kernel(
    const float* __restrict__ x, const float* __restrict__ cb,
    const float* __restrict__ x2, const float* __restrict__ c2,
    const int* __restrict__ fcnt, const int* __restrict__ flist,
    int* __restrict__ out_idx) {
  __shared__ float xs[8][CODE_DIM];
  __shared__ float rv[256];
  __shared__ int ri[256];
  const int nf = *fcnt;
  const int ngr = (nf + 7) >> 3;
  for (int g = blockIdx.x; g < ngr; g += gridDim.x) {
    const int base = g * 8;
    int tok[8];
#pragma unroll
    for (int t = 0; t < 8; ++t) tok[t] = flist[min(base + t, nf - 1)];
    __syncthreads();  // previous group's xs/rv readers done
    if (threadIdx.x < 192) {
#pragma unroll
      for (int t = 0; t < 8; ++t)
        ((float4*)xs[t])[threadIdx.x] =
            ((const float4*)(x + (size_t)tok[t] * CODE_DIM))[threadIdx.x];
    }
    __syncthreads();
    float bv[8]; int bidx[8];
#pragma unroll
    for (int t = 0; t < 8; ++t) { bv[t] = FLTMAX; bidx[t] = 0; }
    for (int kk = 0; kk < NUM_CODES / 256; ++kk) {
      const int k = kk * 256 + threadIdx.x;
      const float4* crow = (const float4*)(cb + (size_t)k * CODE_DIM);
      float a[8];
#pragma unroll
      for (int t = 0; t < 8; ++t) a[t] = 0.f;
      for (int c = 0; c < CODE_DIM / 4; ++c) {
        float4 cv = crow[c];
#pragma unroll
        for (int t = 0; t < 8; ++t) {
          float4 xv = ((float4*)xs[t])[c];
          a[t] += (xv.x * cv.x + xv.y * cv.y) + (xv.z * cv.z + xv.w * cv.w);
        }
      }
      const float c2k = c2[k];
#pragma unroll
      for (int t = 0; t < 8; ++t) {
        float d = (x2[tok[t]] + c2k) - 2.0f * a[t];
        if (d < bv[t]) { bv[t] = d; bidx[t] = k; }
      }
    }
#pragma unroll
    for (int t = 0; t < 8; ++t) {
      __syncthreads();
      rv[threadIdx.x] = bv[t];
      ri[threadIdx.x] = bidx[t];
      __syncthreads();
      for (int s = 128; s > 0; s >>= 1) {
        if (threadIdx.x < s) {
          float ov = rv[threadIdx.x + s];
          int oi = ri[threadIdx.x + s];
          if (ov < rv[threadIdx.x] ||
              (ov == rv[threadIdx.x] && oi < ri[threadIdx.x])) {
            rv[threadIdx.x] = ov;
            ri[threadIdx.x] = oi;
          }
        }
        __syncthreads();
      }
      if (threadIdx.x == 0 && base + t < nf) out_idx[tok[t]] = ri[0];
    }
  }
}

// ---------------------------------------------------------------- gather
__global__ __launch_bounds__(256) void vq_gather_kernel(
    const float* __restrict__ cb, const int* __restrict__ idx,
    float* __restrict__ out) {
  const int wave = threadIdx.x >> 6;
  const int lane = threadIdx.x & 63;
  const int token = blockIdx.x * 4 + wave;
  const int k = idx[token];
  const float4* src = (const float4*)(cb + (size_t)k * CODE_DIM);
  float4* dst = (float4*)(out + (size_t)token * CODE_DIM);
#pragma unroll
  for (int i = 0; i < 3; ++i) dst[lane + 64 * i] = src[lane + 64 * i];
  if (lane == 0) out[(size_t)N_TOKENS * CODE_DIM + token] = (float)k;
}

// ================================================================ fallback
// Round-1 fp32 path (used only if ws_size is too small for the buffers)
#define MT 64
#define KT 128
#define DT 32
#define LDSTRIDE 36

__global__ __launch_bounds__(256) void vq_norms_kernel(
    const float* __restrict__ x, const float* __restrict__ cb,
    float* __restrict__ x2, float* __restrict__ c2) {
  const int wave = threadIdx.x >> 6;
  const int lane = threadIdx.x & 63;
  const int row = blockIdx.x * 4 + wave;
  const float* src;
  float* dst;
  if (row < N_TOKENS) {
    src = x + (size_t)row * CODE_DIM;
    dst = x2 + row;
  } else {
    const int r = row - N_TOKENS;
    if (r >= NUM_CODES) return;
    src = cb + (size_t)r * CODE_DIM;
    dst = c2 + r;
  }
  const float4* s4 = (const float4*)src;
  float acc = 0.f;
#pragma unroll
  for (int i = 0; i < 3; ++i) {
    float4 vv = s4[lane + 64 * i];
    acc += (vv.x * vv.x + vv.y * vv.y) + (vv.z * vv.z + vv.w * vv.w);
  }
#pragma unroll
  for (int off = 32; off > 0; off >>= 1) acc += __shfl_down(acc, off, 64);
  if (lane == 0) *dst = acc;
}

__global__ __launch_bounds__(256) void vq_argmin_kernel(
    const float* __restrict__ x, const float* __restrict__ cb,
    const float* __restrict__ x2, const float* __restrict__ c2,
    int* __restrict__ out_idx) {
  __shared__ float xs[MT * LDSTRIDE];
  __shared__ float cs[KT * LDSTRIDE];
  __shared__ float x2s[MT];
  __shared__ float c2s[KT];
  const int tid = threadIdx.x;
  const int tx = tid & 15;
  const int ty = tid >> 4;
  const int tokBase = blockIdx.x * MT;
  if (tid < MT) x2s[tid] = x2[tokBase + tid];
  float bestv[4];
  int besti[4];
#pragma unroll
  for (int i = 0; i < 4; ++i) { bestv[i] = FLTMAX; besti[i] = 0; }
  const float4* xg = (const float4*)x;
  const float4* cg = (const float4*)cb;
  for (int kt = 0; kt < NUM_CODES / KT; ++kt) {
    const int kBase = kt * KT;
    __syncthreads();
    if (tid < KT) c2s[tid] = c2[kBase + tid];
    float acc[4][8];
#pragma unroll
    for (int i = 0; i < 4; ++i)
#pragma unroll
      for (int j = 0; j < 8; ++j) acc[i][j] = 0.f;
    for (int dc = 0; dc < CODE_DIM / DT; ++dc) {
      __syncthreads();
#pragma unroll
      for (int r = 0; r < 2; ++r) {
        int fidx = tid + 256 * r;
        int row = fidx >> 3, c4 = fidx & 7;
        float4 vv = xg[(size_t)(tokBase + row) * (CODE_DIM / 4) + dc * 8 + c4];
        *(float4*)&xs[row * LDSTRIDE + c4 * 4] = vv;
      }
#pragma unroll
      for (int r = 0; r < 4; ++r) {
        int fidx = tid + 256 * r;
        int row = fidx >> 3, c4 = fidx & 7;
        float4 vv = cg[(size_t)(kBase + row) * (CODE_DIM / 4) + dc * 8 + c4];
        *(float4*)&cs[row * LDSTRIDE + c4 * 4] = vv;
      }
      __syncthreads();
#pragma unroll
      for (int dd = 0; dd < DT / 4; ++dd) {
        float4 xv[4], cv[8];
#pragma unroll
        for (int i = 0; i < 4; ++i)
          xv[i] = *(const float4*)&xs[(ty + 16 * i) * LDSTRIDE + dd * 4];
#pragma unroll
        for (int j = 0; j < 8; ++j)
          cv[j] = *(const float4*)&cs[(tx + 16 * j) * LDSTRIDE + dd * 4];
#pragma unroll
        for (int i = 0; i < 4; ++i)
#pragma unroll
          for (int j = 0; j < 8; ++j)
            acc[i][j] += (xv[i].x * cv[j].x + xv[i].y * cv[j].y) +
                         (xv[i].z * cv[j].z + xv[i].w * cv[j].w);
      }
    }
#pragma unroll
    for (int i = 0; i < 4; ++i) {
      const float xx = x2s[ty + 16 * i];
#pragma unroll
      for (int j = 0; j < 8; ++j) {
        float dist = (xx + c2s[tx + 16 * j]) - 2.0f * acc[i][j];
        int k = kBase + tx + 16 * j;
        if (dist < bestv[i]) { bestv[i] = dist; besti[i] = k; }
      }
    }
  }
  __syncthreads();
  float* rdv = xs;
  int* rdi = (int*)cs;
#pragma unroll
  for (int i = 0; i < 4; ++i) {
    const int m = ty + 16 * i;
    rdv[m * 16 + tx] = bestv[i];
    rdi[m * 16 + tx] = besti[i];
  }
  __syncthreads();
  if (tid < MT) {
    float bv = rdv[tid * 16];
    int bidx = rdi[tid * 16];
#pragma unroll
    for (int t = 1; t < 16; ++t) {
      float vv = rdv[tid * 16 + t];
      int kk = rdi[tid * 16 + t];
      if (vv < bv || (vv == bv && kk < bidx)) { bv = vv; bidx = kk; }
    }
    out_idx[tokBase + tid] = bidx;
  }
}

// ---------------------------------------------------------------- launch
extern "C" void kernel_launch(void* const* d_in, const int* in_sizes, int n_in,
                              void* d_out, int out_size, void* d_ws, size_t ws_size,
                              hipStream_t stream) {
  (void)in_sizes; (void)n_in; (void)out_size;
  const float* x = (const float*)d_in[0];
  const float* cb = (const float*)d_in[1];
  float* out = (float*)d_out;

  // ws carve (fp16 MFMA path)
  char* w = (char*)d_ws;
  unsigned short* xh = (unsigned short*)w;  w += (size_t)N_TOKENS * CODE_DIM * 2;
  unsigned short* ch = (unsigned short*)w;  w += (size_t)NUM_CODES * CODE_DIM * 2;
  float* x2 = (float*)w;  w += (size_t)N_TOKENS * 4;
  float* c2 = (float*)w;  w += (size_t)NUM_CODES * 4;
  int* idx = (int*)w;     w += (size_t)N_TOKENS * 4;
  int* flist = (int*)w;   w += (size_t)N_TOKENS * 4;
  int* fcnt = (int*)w;    w += 256;
  const size_t need = (size_t)(w - (char*)d_ws);

  if (ws_size >= need) {
    vq_convert_kernel<<<(N_TOKENS + NUM_CODES) / 4, 256, 0, stream>>>(
        x, cb, xh, ch, x2, c2, fcnt);
    vq_mfma_kernel<<<N_TOKENS / BT, 512, 0, stream>>>(
        xh, ch, c2, idx, fcnt, flist);
    vq_rescan_kernel<<<512, 256, 0, stream>>>(x, cb, x2, c2, fcnt, flist, idx);
    vq_gather_kernel<<<N_TOKENS / 4, 256, 0, stream>>>(cb, idx, out);
  } else {
    // fallback: round-1 fp32 path
    float* fx2 = (float*)d_ws;
    float* fc2 = fx2 + N_TOKENS;
    int* fidx = (int*)(fc2 + NUM_CODES);
    vq_norms_kernel<<<(N_TOKENS + NUM_CODES + 3) / 4, 256, 0, stream>>>(x, cb, fx2, fc2);
    vq_argmin_kernel<<<N_TOKENS / MT, 256, 0, stream>>>(x, cb, fx2, fc2, fidx);
    vq_gather_kernel<<<N_TOKENS / 4, 256, 0, stream>>>(cb, fidx, out);
  }
}